// Round 14
// baseline (130.392 us; speedup 1.0000x reference)
//
#include <hip/hip_runtime.h>
#include <hip/hip_bf16.h>
#include <stdint.h>

#define S    5
#define F    12
#define E    32
#define OUTD 64
#define SF   60
#define TB   32      // batches per block (16 per wave)
#define NTHR 128     // 2 waves, fully independent

// d_ws layout (u32 offsets)
#define WS_W1HI  0
#define WS_W1LO  512
#define WS_WQH   1024
#define WS_WQL   2560
#define WS_WOH   4096
#define WS_WOL   4608
#define WS_W3H   5120
#define WS_W3L   10240
#define WS_TOTAL 15360

typedef __attribute__((ext_vector_type(8))) short bf16x8;
typedef __attribute__((ext_vector_type(4))) float f32x4;
typedef __attribute__((ext_vector_type(2))) float f32x2;

union FragU { bf16x8 v; uint32_t u[4]; uint4 q; };

__device__ __forceinline__ f32x2 pkfma(f32x2 a, f32x2 b, f32x2 c) {
  return __builtin_elementwise_fma(a, b, c);
}

// HW bf16 conversion (RNE) — compiler emits v_cvt_pk_bf16_f32
__device__ __forceinline__ uint32_t pack2(float lo, float hi) {
  __hip_bfloat16 a = __float2bfloat16(lo);
  __hip_bfloat16 b = __float2bfloat16(hi);
  uint16_t ua = __builtin_bit_cast(uint16_t, a);
  uint16_t ub = __builtin_bit_cast(uint16_t, b);
  return (uint32_t)ua | ((uint32_t)ub << 16);
}
__device__ __forceinline__ f32x2 up2v(uint32_t w) {
  union { uint32_t u; float f; } a, b;
  a.u = w << 16; b.u = w & 0xffff0000u;
  f32x2 r; r[0] = a.f; r[1] = b.f; return r;
}
__device__ __forceinline__ uint16_t f2bf(float f) {   // prep only
  union { float f; uint32_t u; } c; c.f = f;
  uint32_t u = c.u + 0x7fffu + ((c.u >> 16) & 1u);
  return (uint16_t)(u >> 16);
}
__device__ __forceinline__ float bf2f(uint16_t h) {
  union { uint32_t u; float f; } c; c.u = ((uint32_t)h) << 16; return c.f;
}

// ---------------- prep: pack hi/lo bf16 weight planes into d_ws ----------------
__global__ void prep_weights(const float* __restrict__ W1, const float* __restrict__ Wqkv,
                             const float* __restrict__ Wo, const float* __restrict__ W3,
                             uint32_t* __restrict__ ws) {
  int i = blockIdx.x * blockDim.x + threadIdx.x;
  if (i >= WS_TOTAL) return;
  const float* W; int ldk, K, r, j; bool lo;
  if (i < 1024)      { W = W1;   ldk = 12;  K = 12;  int t = i;        lo = t >= 512;  t &= 511;  r = t >> 4; j = t & 15; }
  else if (i < 4096) { W = Wqkv; ldk = 32;  K = 32;  int t = i - 1024; lo = t >= 1536; t %= 1536; r = t >> 4; j = t & 15; }
  else if (i < 5120) { W = Wo;   ldk = 32;  K = 32;  int t = i - 4096; lo = t >= 512;  t &= 511;  r = t >> 4; j = t & 15; }
  else               { W = W3;   ldk = 160; K = 160; int t = i - 5120; lo = t >= 5120; t %= 5120; r = t / 80; j = t % 80; }
  float v2[2];
#pragma unroll
  for (int c = 0; c < 2; ++c) {
    int k = 2 * j + c;
    float w = 0.f;
    if (k < K) {
      w = W[r * ldk + k];
      if (lo) w = w - bf2f(f2bf(w));
    }
    v2[c] = w;
  }
  ws[i] = (uint32_t)f2bf(v2[0]) | (((uint32_t)f2bf(v2[1])) << 16);
}

__global__ __launch_bounds__(NTHR, 2) void fused_exec_encoder(
    const float* __restrict__ x,
    const float* __restrict__ b1,
    const float* __restrict__ g1,   const float* __restrict__ be1,
    const float* __restrict__ bqkv,
    const float* __restrict__ bo,
    const float* __restrict__ g2,   const float* __restrict__ be2,
    const float* __restrict__ b3,
    const float* __restrict__ g3,   const float* __restrict__ be3,
    const uint32_t* __restrict__ ws,
    float* __restrict__ out)
{
  // qkv:[160 rows][48 u32]  (96 bf16/row, 12x16B chunks, chunk^ (row&3) swizzle) = 30720 B
  // q chunks 0-3 (o overwrites after attention), k chunks 4-7 (h2 overwrites after attention),
  // v chunks 8-11.  NO separate h buffer: P2 B-frags via ds_bpermute, residual in regs.
  __shared__ __align__(16) uint32_t qkv_lds[160 * 48];

  const int tid  = threadIdx.x;
  const int lane = tid & 63;
  const int wv   = tid >> 6;
  const int li   = lane & 15;
  const int g    = lane >> 4;
  const int rowW = wv * 80;
  const long long b0 = (long long)blockIdx.x * TB;

  // bpermute source-lane addresses for P2 B-fragment gather (within same li column)
  const int addrA = ((li + 16 * ((2 * g) & 3)) << 2);       // u32 k=0,1
  const int addrB = ((li + 16 * ((2 * g + 1) & 3)) << 2);   // u32 k=2,3
  const bool gl = (g < 2);

  // ======== x prefetch ========
  float4 xpa[5], xpb[5], xpc[5];
#pragma unroll
  for (int mt = 0; mt < 5; ++mt) {
    int tokL = rowW + mt * 16 + li;
    const float* xp = x + (b0 * S + tokL) * F;
    if (g == 0) { xpa[mt] = *(const float4*)(xp);  xpb[mt] = *(const float4*)(xp + 4); }
    else if (g == 1) { xpc[mt] = *(const float4*)(xp + 8); }
  }

  // ======== weight fragments + params ========
  FragU whi[2], wlo[2], wq[6], wql[6], wof[2], wolf[2];
#pragma unroll
  for (int t = 0; t < 2; ++t) {
    whi[t].q  = *(const uint4*)&ws[WS_W1HI + (t * 16 + li) * 16 + g * 4];
    wlo[t].q  = *(const uint4*)&ws[WS_W1LO + (t * 16 + li) * 16 + g * 4];
    wof[t].q  = *(const uint4*)&ws[WS_WOH  + (t * 16 + li) * 16 + g * 4];
    wolf[t].q = *(const uint4*)&ws[WS_WOL  + (t * 16 + li) * 16 + g * 4];
  }
#pragma unroll
  for (int ft = 0; ft < 6; ++ft) {
    wq[ft].q  = *(const uint4*)&ws[WS_WQH + (ft * 16 + li) * 16 + g * 4];
    wql[ft].q = *(const uint4*)&ws[WS_WQL + (ft * 16 + li) * 16 + g * 4];
  }
  f32x4 binit[2], bq[6], boin[2];
  f32x2 g1p[4], e1p[4], g2p[4], e2p[4];
#pragma unroll
  for (int t = 0; t < 2; ++t) {
    binit[t] = *(const f32x4*)&b1[t * 16 + g * 4];
    boin[t]  = *(const f32x4*)&bo[t * 16 + g * 4];
#pragma unroll
    for (int p = 0; p < 2; ++p) {
      g1p[t*2+p] = *(const f32x2*)&g1[t * 16 + g * 4 + p * 2];
      e1p[t*2+p] = *(const f32x2*)&be1[t * 16 + g * 4 + p * 2];
      g2p[t*2+p] = *(const f32x2*)&g2[t * 16 + g * 4 + p * 2];
      e2p[t*2+p] = *(const f32x2*)&be2[t * 16 + g * 4 + p * 2];
    }
  }
#pragma unroll
  for (int ft = 0; ft < 6; ++ft) bq[ft] = *(const f32x4*)&bqkv[ft * 16 + g * 4];

  const f32x2 z2 = {0.f, 0.f};

  // h (post-P1) kept in registers: pkm[mt][j] = packed bf16 pair j of this lane's quads
  uint32_t pkm[5][4];

  // ================= P1: slot_encoder (LN result stays in registers) =================
  {
#pragma unroll
    for (int mt = 0; mt < 5; ++mt) {
      FragU xb;
      xb.u[0] = xb.u[1] = xb.u[2] = xb.u[3] = 0u;
      if (g == 0) {
        xb.u[0] = pack2(xpa[mt].x, xpa[mt].y); xb.u[1] = pack2(xpa[mt].z, xpa[mt].w);
        xb.u[2] = pack2(xpb[mt].x, xpb[mt].y); xb.u[3] = pack2(xpb[mt].z, xpb[mt].w);
      } else if (g == 1) {
        xb.u[0] = pack2(xpc[mt].x, xpc[mt].y); xb.u[1] = pack2(xpc[mt].z, xpc[mt].w);
      }
      __builtin_amdgcn_s_setprio(1);
      f32x4 a0 = __builtin_amdgcn_mfma_f32_16x16x32_bf16(whi[0].v, xb.v, binit[0], 0, 0, 0);
      a0       = __builtin_amdgcn_mfma_f32_16x16x32_bf16(wlo[0].v, xb.v, a0,       0, 0, 0);
      f32x4 a1 = __builtin_amdgcn_mfma_f32_16x16x32_bf16(whi[1].v, xb.v, binit[1], 0, 0, 0);
      a1       = __builtin_amdgcn_mfma_f32_16x16x32_bf16(wlo[1].v, xb.v, a1,       0, 0, 0);
      __builtin_amdgcn_s_setprio(0);
      f32x2 vv2[4];
      vv2[0][0]=a0[0]; vv2[0][1]=a0[1]; vv2[1][0]=a0[2]; vv2[1][1]=a0[3];
      vv2[2][0]=a1[0]; vv2[2][1]=a1[1]; vv2[3][0]=a1[2]; vv2[3][1]=a1[3];
      f32x2 s2 = (vv2[0] + vv2[1]) + (vv2[2] + vv2[3]);
      f32x2 q2 = vv2[0] * vv2[0];
      q2 = pkfma(vv2[1], vv2[1], q2); q2 = pkfma(vv2[2], vv2[2], q2); q2 = pkfma(vv2[3], vv2[3], q2);
      float sm = s2[0] + s2[1], sq = q2[0] + q2[1];
      sm += __shfl_xor(sm, 16); sm += __shfl_xor(sm, 32);
      sq += __shfl_xor(sq, 16); sq += __shfl_xor(sq, 32);
      float mean = sm * (1.f / 32.f);
      float inv  = rsqrtf(sq * (1.f / 32.f) - mean * mean + 1e-5f);
      f32x2 mean2 = {mean, mean}, inv2 = {inv, inv};
#pragma unroll
      for (int j = 0; j < 4; ++j) {
        f32x2 u = (vv2[j] - mean2) * inv2;
        u = pkfma(u, g1p[j], e1p[j]);
        u = __builtin_elementwise_max(u, z2);
        pkm[mt][j] = pack2(u[0], u[1]);
      }
    }
  }

  // ================= P2: QKV projection (B-frags gathered via ds_bpermute) =================
  {
#pragma unroll
    for (int mt = 0; mt < 5; ++mt) {
      int tokL = rowW + mt * 16 + li;
      FragU hb;
      {
        int p0 = __builtin_amdgcn_ds_bpermute(addrA, (int)pkm[mt][0]);
        int p2 = __builtin_amdgcn_ds_bpermute(addrA, (int)pkm[mt][2]);
        int p1 = __builtin_amdgcn_ds_bpermute(addrA, (int)pkm[mt][1]);
        int p3 = __builtin_amdgcn_ds_bpermute(addrA, (int)pkm[mt][3]);
        int q0 = __builtin_amdgcn_ds_bpermute(addrB, (int)pkm[mt][0]);
        int q2b = __builtin_amdgcn_ds_bpermute(addrB, (int)pkm[mt][2]);
        int q1 = __builtin_amdgcn_ds_bpermute(addrB, (int)pkm[mt][1]);
        int q3 = __builtin_amdgcn_ds_bpermute(addrB, (int)pkm[mt][3]);
        hb.u[0] = gl ? (uint32_t)p0 : (uint32_t)p2;
        hb.u[1] = gl ? (uint32_t)p1 : (uint32_t)p3;
        hb.u[2] = gl ? (uint32_t)q0 : (uint32_t)q2b;
        hb.u[3] = gl ? (uint32_t)q1 : (uint32_t)q3;
      }
      __builtin_amdgcn_s_setprio(1);
#pragma unroll
      for (int ft = 0; ft < 6; ++ft) {
        f32x4 acc = __builtin_amdgcn_mfma_f32_16x16x32_bf16(wq[ft].v,  hb.v, bq[ft], 0, 0, 0);
        acc       = __builtin_amdgcn_mfma_f32_16x16x32_bf16(wql[ft].v, hb.v, acc,    0, 0, 0);
        int chq = (ft * 2 + (g >> 1)) ^ (tokL & 3);
        uint2 wr; wr.x = pack2(acc[0], acc[1]); wr.y = pack2(acc[2], acc[3]);
        *(uint2*)&qkv_lds[tokL * 48 + chq * 4 + (g & 1) * 2] = wr;
      }
      __builtin_amdgcn_s_setprio(0);
    }
  }

  // ================= attention (packed f32 math) =================
  {
    int b_l = wv * 16 + (lane >> 2);
    int hh  = (lane >> 1) & 1;
    int cq  = hh * 2 + (lane & 1);

    f32x2 q2[5][4]; uint32_t kp[5][4], vp[5][4];
#pragma unroll
    for (int s = 0; s < 5; ++s) {
      int tok = b_l * 5 + s, key = tok & 3;
      uint4 qv = *(const uint4*)&qkv_lds[tok * 48 + (cq ^ key) * 4];
      q2[s][0] = up2v(qv.x); q2[s][1] = up2v(qv.y);
      q2[s][2] = up2v(qv.z); q2[s][3] = up2v(qv.w);
      uint4 kv = *(const uint4*)&qkv_lds[tok * 48 + ((4 + cq) ^ key) * 4];
      kp[s][0] = kv.x; kp[s][1] = kv.y; kp[s][2] = kv.z; kp[s][3] = kv.w;
      uint4 vv4 = *(const uint4*)&qkv_lds[tok * 48 + ((8 + cq) ^ key) * 4];
      vp[s][0] = vv4.x; vp[s][1] = vv4.y; vp[s][2] = vv4.z; vp[s][3] = vv4.w;
    }
    float sc[5][5];
#pragma unroll
    for (int s2 = 0; s2 < 5; ++s2) {
      f32x2 k0 = up2v(kp[s2][0]), k1 = up2v(kp[s2][1]);
      f32x2 k2 = up2v(kp[s2][2]), k3 = up2v(kp[s2][3]);
#pragma unroll
      for (int s1 = 0; s1 < 5; ++s1) {
        f32x2 acc = q2[s1][0] * k0;
        acc = pkfma(q2[s1][1], k1, acc);
        acc = pkfma(q2[s1][2], k2, acc);
        acc = pkfma(q2[s1][3], k3, acc);
        sc[s1][s2] = acc[0] + acc[1];
      }
    }
#pragma unroll
    for (int s1 = 0; s1 < 5; ++s1)
#pragma unroll
      for (int s2 = 0; s2 < 5; ++s2) {
        float p = sc[s1][s2];
        p += __shfl_xor(p, 1);
        sc[s1][s2] = p;
      }
    const float C = 0.36067376022224085f;     // 0.25 * log2(e)
#pragma unroll
    for (int s1 = 0; s1 < 5; ++s1) {
      float m = fmaxf(fmaxf(fmaxf(sc[s1][0], sc[s1][1]), fmaxf(sc[s1][2], sc[s1][3])), sc[s1][4]);
      float ssum = 0.f;
#pragma unroll
      for (int s2 = 0; s2 < 5; ++s2) {
        float e = __builtin_amdgcn_exp2f((sc[s1][s2] - m) * C);
        sc[s1][s2] = e; ssum += e;
      }
      float rs = __builtin_amdgcn_rcpf(ssum);
#pragma unroll
      for (int s2 = 0; s2 < 5; ++s2) sc[s1][s2] *= rs;
    }
    f32x2 o2[5][4];
#pragma unroll
    for (int s1 = 0; s1 < 5; ++s1)
#pragma unroll
      for (int j = 0; j < 4; ++j) o2[s1][j] = z2;
#pragma unroll
    for (int s2 = 0; s2 < 5; ++s2) {
      f32x2 v0 = up2v(vp[s2][0]), v1 = up2v(vp[s2][1]);
      f32x2 v2 = up2v(vp[s2][2]), v3 = up2v(vp[s2][3]);
#pragma unroll
      for (int s1 = 0; s1 < 5; ++s1) {
        f32x2 pp = {sc[s1][s2], sc[s1][s2]};
        o2[s1][0] = pkfma(pp, v0, o2[s1][0]);
        o2[s1][1] = pkfma(pp, v1, o2[s1][1]);
        o2[s1][2] = pkfma(pp, v2, o2[s1][2]);
        o2[s1][3] = pkfma(pp, v3, o2[s1][3]);
      }
    }
#pragma unroll
    for (int s1 = 0; s1 < 5; ++s1) {
      int tok = b_l * 5 + s1;
      uint4 wr;
      wr.x = pack2(o2[s1][0][0], o2[s1][0][1]); wr.y = pack2(o2[s1][1][0], o2[s1][1][1]);
      wr.z = pack2(o2[s1][2][0], o2[s1][2][1]); wr.w = pack2(o2[s1][3][0], o2[s1][3][1]);
      *(uint4*)&qkv_lds[tok * 48 + (cq ^ (tok & 3)) * 4] = wr;
    }
  }

  // ================= P3: out_proj + residual(regs) + LN2 -> h2 into k-chunks =================
  {
#pragma unroll
    for (int mt = 0; mt < 5; ++mt) {
      int tokL = rowW + mt * 16 + li;
      int ch = g ^ (tokL & 3);
      uint4 ov = *(const uint4*)&qkv_lds[tokL * 48 + ch * 4];
      FragU ob; ob.q = ov;
      __builtin_amdgcn_s_setprio(1);
      f32x4 a0 = __builtin_amdgcn_mfma_f32_16x16x32_bf16(wof[0].v,  ob.v, boin[0], 0, 0, 0);
      a0       = __builtin_amdgcn_mfma_f32_16x16x32_bf16(wolf[0].v, ob.v, a0,      0, 0, 0);
      f32x4 a1 = __builtin_amdgcn_mfma_f32_16x16x32_bf16(wof[1].v,  ob.v, boin[1], 0, 0, 0);
      a1       = __builtin_amdgcn_mfma_f32_16x16x32_bf16(wolf[1].v, ob.v, a1,      0, 0, 0);
      __builtin_amdgcn_s_setprio(0);
      f32x2 vv2[4];
      {
        f32x2 r0 = up2v(pkm[mt][0]), r1 = up2v(pkm[mt][1]);
        f32x2 r2 = up2v(pkm[mt][2]), r3 = up2v(pkm[mt][3]);
        f32x2 p0; p0[0] = a0[0]; p0[1] = a0[1];
        f32x2 p1; p1[0] = a0[2]; p1[1] = a0[3];
        f32x2 p2; p2[0] = a1[0]; p2[1] = a1[1];
        f32x2 p3; p3[0] = a1[2]; p3[1] = a1[3];
        vv2[0] = p0 + r0; vv2[1] = p1 + r1; vv2[2] = p2 + r2; vv2[3] = p3 + r3;
      }
      f32x2 s2 = (vv2[0] + vv2[1]) + (vv2[2] + vv2[3]);
      f32x2 q2 = vv2[0] * vv2[0];
      q2 = pkfma(vv2[1], vv2[1], q2); q2 = pkfma(vv2[2], vv2[2], q2); q2 = pkfma(vv2[3], vv2[3], q2);
      float sm = s2[0] + s2[1], sq = q2[0] + q2[1];
      sm += __shfl_xor(sm, 16); sm += __shfl_xor(sm, 32);
      sq += __shfl_xor(sq, 16); sq += __shfl_xor(sq, 32);
      float mean = sm * (1.f / 32.f);
      float inv  = rsqrtf(sq * (1.f / 32.f) - mean * mean + 1e-5f);
      f32x2 mean2 = {mean, mean}, inv2 = {inv, inv};
      uint32_t pk[4];
#pragma unroll
      for (int j = 0; j < 4; ++j) {
        f32x2 u = (vv2[j] - mean2) * inv2;
        u = pkfma(u, g2p[j], e2p[j]);
        pk[j] = pack2(u[0], u[1]);
      }
      // h2 -> chunks 4..7 (old k region, dead after attention)
#pragma unroll
      for (int t = 0; t < 2; ++t) {
        int chh = (4 + t * 2 + (g >> 1)) ^ (tokL & 3);
        uint2 wr; wr.x = pk[t*2]; wr.y = pk[t*2+1];
        *(uint2*)&qkv_lds[tokL * 48 + chh * 4 + (g & 1) * 2] = wr;
      }
    }
  }

  // ================= P4: output_proj (160 -> 64) + LN3 =================
  {
    int batL = wv * 16 + li;
    f32x4 acc[4];
#pragma unroll
    for (int ot = 0; ot < 4; ++ot) acc[ot] = *(const f32x4*)&b3[ot * 16 + g * 4];
#pragma unroll
    for (int kt = 0; kt < 5; ++kt) {
      int tokL = batL * 5 + kt;
      int ch = (4 + g) ^ (tokL & 3);
      uint4 hv = *(const uint4*)&qkv_lds[tokL * 48 + ch * 4];
      FragU hb; hb.q = hv;
      __builtin_amdgcn_s_setprio(1);
#pragma unroll
      for (int ot = 0; ot < 4; ++ot) {
        FragU fh, fl;
        fh.q = *(const uint4*)&ws[WS_W3H + (ot * 16 + li) * 80 + kt * 16 + g * 4];
        fl.q = *(const uint4*)&ws[WS_W3L + (ot * 16 + li) * 80 + kt * 16 + g * 4];
        acc[ot] = __builtin_amdgcn_mfma_f32_16x16x32_bf16(fh.v, hb.v, acc[ot], 0, 0, 0);
        acc[ot] = __builtin_amdgcn_mfma_f32_16x16x32_bf16(fl.v, hb.v, acc[ot], 0, 0, 0);
      }
      __builtin_amdgcn_s_setprio(0);
    }
    f32x2 a2[8];
#pragma unroll
    for (int ot = 0; ot < 4; ++ot) {
      a2[ot*2][0] = acc[ot][0]; a2[ot*2][1] = acc[ot][1];
      a2[ot*2+1][0] = acc[ot][2]; a2[ot*2+1][1] = acc[ot][3];
    }
    f32x2 s2v = ((a2[0] + a2[1]) + (a2[2] + a2[3])) + ((a2[4] + a2[5]) + (a2[6] + a2[7]));
    f32x2 q2v = a2[0] * a2[0];
#pragma unroll
    for (int j = 1; j < 8; ++j) q2v = pkfma(a2[j], a2[j], q2v);
    float sm = s2v[0] + s2v[1], sq = q2v[0] + q2v[1];
    sm += __shfl_xor(sm, 16); sm += __shfl_xor(sm, 32);
    sq += __shfl_xor(sq, 16); sq += __shfl_xor(sq, 32);
    float mean = sm * (1.f / 64.f);
    float inv  = rsqrtf(sq * (1.f / 64.f) - mean * mean + 1e-5f);
    f32x2 mean2 = {mean, mean}, inv2 = {inv, inv};
    float* op = out + (size_t)(b0 + batL) * OUTD;
#pragma unroll
    for (int ot = 0; ot < 4; ++ot) {
      f32x2 u0 = (a2[ot*2]   - mean2) * inv2;
      f32x2 u1 = (a2[ot*2+1] - mean2) * inv2;
      u0 = pkfma(u0, *(const f32x2*)&g3[ot * 16 + g * 4],     *(const f32x2*)&be3[ot * 16 + g * 4]);
      u1 = pkfma(u1, *(const f32x2*)&g3[ot * 16 + g * 4 + 2], *(const f32x2*)&be3[ot * 16 + g * 4 + 2]);
      float4 st; st.x = u0[0]; st.y = u0[1]; st.z = u1[0]; st.w = u1[1];
      *(float4*)&op[ot * 16 + g * 4] = st;
    }
  }
}

extern "C" void kernel_launch(void* const* d_in, const int* in_sizes, int n_in,
                              void* d_out, int out_size, void* d_ws, size_t ws_size,
                              hipStream_t stream) {
  const float* x    = (const float*)d_in[0];
  const float* W1   = (const float*)d_in[1];
  const float* b1   = (const float*)d_in[2];
  const float* g1   = (const float*)d_in[3];
  const float* be1  = (const float*)d_in[4];
  const float* Wqkv = (const float*)d_in[5];
  const float* bqkv = (const float*)d_in[6];
  const float* Wo   = (const float*)d_in[7];
  const float* bo   = (const float*)d_in[8];
  const float* g2   = (const float*)d_in[9];
  const float* be2  = (const float*)d_in[10];
  const float* W3   = (const float*)d_in[11];
  const float* b3   = (const float*)d_in[12];
  const float* g3   = (const float*)d_in[13];
  const float* be3  = (const float*)d_in[14];
  float* out = (float*)d_out;
  uint32_t* ws = (uint32_t*)d_ws;

  prep_weights<<<dim3((WS_TOTAL + 255) / 256), dim3(256), 0, stream>>>(W1, Wqkv, Wo, W3, ws);

  const int nbatch  = in_sizes[0] / SF;   // 262144
  const int nblocks = nbatch / TB;        // 8192

  fused_exec_encoder<<<dim3(nblocks), dim3(NTHR), 0, stream>>>(
      x, b1, g1, be1, bqkv, bo, g2, be2, b3, g3, be3, ws, out);
}

// Round 15
// 122.587 us; speedup vs baseline: 1.0637x; 1.0637x over previous
//
#include <hip/hip_runtime.h>
#include <hip/hip_bf16.h>
#include <stdint.h>

#define S    5
#define F    12
#define E    32
#define OUTD 64
#define SF   60
#define TB   16      // batches per block (one wave)
#define NTHR 64      // 1 wave per block -> fine-grained occupancy packing

// d_ws layout (u32 offsets)
#define WS_W1HI  0
#define WS_W1LO  512
#define WS_WQH   1024
#define WS_WQL   2560
#define WS_WOH   4096
#define WS_WOL   4608
#define WS_W3H   5120
#define WS_W3L   10240
#define WS_TOTAL 15360

typedef __attribute__((ext_vector_type(8))) short bf16x8;
typedef __attribute__((ext_vector_type(4))) float f32x4;
typedef __attribute__((ext_vector_type(2))) float f32x2;

union FragU { bf16x8 v; uint32_t u[4]; uint4 q; };

__device__ __forceinline__ f32x2 pkfma(f32x2 a, f32x2 b, f32x2 c) {
  return __builtin_elementwise_fma(a, b, c);
}

// HW bf16 conversion (RNE) — compiler emits v_cvt_pk_bf16_f32
__device__ __forceinline__ uint32_t pack2(float lo, float hi) {
  __hip_bfloat16 a = __float2bfloat16(lo);
  __hip_bfloat16 b = __float2bfloat16(hi);
  uint16_t ua = __builtin_bit_cast(uint16_t, a);
  uint16_t ub = __builtin_bit_cast(uint16_t, b);
  return (uint32_t)ua | ((uint32_t)ub << 16);
}
__device__ __forceinline__ f32x2 up2v(uint32_t w) {
  union { uint32_t u; float f; } a, b;
  a.u = w << 16; b.u = w & 0xffff0000u;
  f32x2 r; r[0] = a.f; r[1] = b.f; return r;
}
__device__ __forceinline__ uint16_t f2bf(float f) {   // prep only
  union { float f; uint32_t u; } c; c.f = f;
  uint32_t u = c.u + 0x7fffu + ((c.u >> 16) & 1u);
  return (uint16_t)(u >> 16);
}
__device__ __forceinline__ float bf2f(uint16_t h) {
  union { uint32_t u; float f; } c; c.u = ((uint32_t)h) << 16; return c.f;
}

// ---------------- prep: pack hi/lo bf16 weight planes into d_ws ----------------
__global__ void prep_weights(const float* __restrict__ W1, const float* __restrict__ Wqkv,
                             const float* __restrict__ Wo, const float* __restrict__ W3,
                             uint32_t* __restrict__ ws) {
  int i = blockIdx.x * blockDim.x + threadIdx.x;
  if (i >= WS_TOTAL) return;
  const float* W; int ldk, K, r, j; bool lo;
  if (i < 1024)      { W = W1;   ldk = 12;  K = 12;  int t = i;        lo = t >= 512;  t &= 511;  r = t >> 4; j = t & 15; }
  else if (i < 4096) { W = Wqkv; ldk = 32;  K = 32;  int t = i - 1024; lo = t >= 1536; t %= 1536; r = t >> 4; j = t & 15; }
  else if (i < 5120) { W = Wo;   ldk = 32;  K = 32;  int t = i - 4096; lo = t >= 512;  t &= 511;  r = t >> 4; j = t & 15; }
  else               { W = W3;   ldk = 160; K = 160; int t = i - 5120; lo = t >= 5120; t %= 5120; r = t / 80; j = t % 80; }
  float v2[2];
#pragma unroll
  for (int c = 0; c < 2; ++c) {
    int k = 2 * j + c;
    float w = 0.f;
    if (k < K) {
      w = W[r * ldk + k];
      if (lo) w = w - bf2f(f2bf(w));
    }
    v2[c] = w;
  }
  ws[i] = (uint32_t)f2bf(v2[0]) | (((uint32_t)f2bf(v2[1])) << 16);
}

__global__ __launch_bounds__(NTHR, 2) void fused_exec_encoder(
    const float* __restrict__ x,
    const float* __restrict__ b1,
    const float* __restrict__ g1,   const float* __restrict__ be1,
    const float* __restrict__ bqkv,
    const float* __restrict__ bo,
    const float* __restrict__ g2,   const float* __restrict__ be2,
    const float* __restrict__ b3,
    const float* __restrict__ g3,   const float* __restrict__ be3,
    const uint32_t* __restrict__ ws,
    float* __restrict__ out)
{
  // qkv:[80 rows][48 u32]  (96 bf16/row, 12x16B chunks, chunk^ (row&3) swizzle) = 15360 B
  // q chunks 0-3 (o overwrites after attention), k chunks 4-7 (h2 overwrites after attention),
  // v chunks 8-11.  NO separate h buffer: P2 B-frags via ds_bpermute, residual in regs.
  __shared__ __align__(16) uint32_t qkv_lds[80 * 48];

  const int lane = threadIdx.x & 63;
  const int li   = lane & 15;
  const int g    = lane >> 4;
  const long long b0 = (long long)blockIdx.x * TB;

  // bpermute source-lane addresses for P2 B-fragment gather (within same li column)
  const int addrA = ((li + 16 * ((2 * g) & 3)) << 2);       // u32 k=0,1
  const int addrB = ((li + 16 * ((2 * g + 1) & 3)) << 2);   // u32 k=2,3
  const bool gl = (g < 2);

  // ======== x prefetch ========
  float4 xpa[5], xpb[5], xpc[5];
#pragma unroll
  for (int mt = 0; mt < 5; ++mt) {
    int tokL = mt * 16 + li;
    const float* xp = x + (b0 * S + tokL) * F;
    if (g == 0) { xpa[mt] = *(const float4*)(xp);  xpb[mt] = *(const float4*)(xp + 4); }
    else if (g == 1) { xpc[mt] = *(const float4*)(xp + 8); }
  }

  // ======== weight fragments + params ========
  FragU whi[2], wlo[2], wq[6], wql[6], wof[2], wolf[2];
#pragma unroll
  for (int t = 0; t < 2; ++t) {
    whi[t].q  = *(const uint4*)&ws[WS_W1HI + (t * 16 + li) * 16 + g * 4];
    wlo[t].q  = *(const uint4*)&ws[WS_W1LO + (t * 16 + li) * 16 + g * 4];
    wof[t].q  = *(const uint4*)&ws[WS_WOH  + (t * 16 + li) * 16 + g * 4];
    wolf[t].q = *(const uint4*)&ws[WS_WOL  + (t * 16 + li) * 16 + g * 4];
  }
#pragma unroll
  for (int ft = 0; ft < 6; ++ft) {
    wq[ft].q  = *(const uint4*)&ws[WS_WQH + (ft * 16 + li) * 16 + g * 4];
    wql[ft].q = *(const uint4*)&ws[WS_WQL + (ft * 16 + li) * 16 + g * 4];
  }
  f32x4 binit[2], bq[6], boin[2];
  f32x2 g1p[4], e1p[4], g2p[4], e2p[4];
#pragma unroll
  for (int t = 0; t < 2; ++t) {
    binit[t] = *(const f32x4*)&b1[t * 16 + g * 4];
    boin[t]  = *(const f32x4*)&bo[t * 16 + g * 4];
#pragma unroll
    for (int p = 0; p < 2; ++p) {
      g1p[t*2+p] = *(const f32x2*)&g1[t * 16 + g * 4 + p * 2];
      e1p[t*2+p] = *(const f32x2*)&be1[t * 16 + g * 4 + p * 2];
      g2p[t*2+p] = *(const f32x2*)&g2[t * 16 + g * 4 + p * 2];
      e2p[t*2+p] = *(const f32x2*)&be2[t * 16 + g * 4 + p * 2];
    }
  }
#pragma unroll
  for (int ft = 0; ft < 6; ++ft) bq[ft] = *(const f32x4*)&bqkv[ft * 16 + g * 4];

  const f32x2 z2 = {0.f, 0.f};

  // h (post-P1) kept in registers: pkm[mt][j] = packed bf16 pair j of this lane's quads
  uint32_t pkm[5][4];

  // ================= P1: slot_encoder (LN result stays in registers) =================
  {
#pragma unroll
    for (int mt = 0; mt < 5; ++mt) {
      FragU xb;
      xb.u[0] = xb.u[1] = xb.u[2] = xb.u[3] = 0u;
      if (g == 0) {
        xb.u[0] = pack2(xpa[mt].x, xpa[mt].y); xb.u[1] = pack2(xpa[mt].z, xpa[mt].w);
        xb.u[2] = pack2(xpb[mt].x, xpb[mt].y); xb.u[3] = pack2(xpb[mt].z, xpb[mt].w);
      } else if (g == 1) {
        xb.u[0] = pack2(xpc[mt].x, xpc[mt].y); xb.u[1] = pack2(xpc[mt].z, xpc[mt].w);
      }
      f32x4 a0 = __builtin_amdgcn_mfma_f32_16x16x32_bf16(whi[0].v, xb.v, binit[0], 0, 0, 0);
      a0       = __builtin_amdgcn_mfma_f32_16x16x32_bf16(wlo[0].v, xb.v, a0,       0, 0, 0);
      f32x4 a1 = __builtin_amdgcn_mfma_f32_16x16x32_bf16(whi[1].v, xb.v, binit[1], 0, 0, 0);
      a1       = __builtin_amdgcn_mfma_f32_16x16x32_bf16(wlo[1].v, xb.v, a1,       0, 0, 0);
      f32x2 vv2[4];
      vv2[0][0]=a0[0]; vv2[0][1]=a0[1]; vv2[1][0]=a0[2]; vv2[1][1]=a0[3];
      vv2[2][0]=a1[0]; vv2[2][1]=a1[1]; vv2[3][0]=a1[2]; vv2[3][1]=a1[3];
      f32x2 s2 = (vv2[0] + vv2[1]) + (vv2[2] + vv2[3]);
      f32x2 q2 = vv2[0] * vv2[0];
      q2 = pkfma(vv2[1], vv2[1], q2); q2 = pkfma(vv2[2], vv2[2], q2); q2 = pkfma(vv2[3], vv2[3], q2);
      float sm = s2[0] + s2[1], sq = q2[0] + q2[1];
      sm += __shfl_xor(sm, 16); sm += __shfl_xor(sm, 32);
      sq += __shfl_xor(sq, 16); sq += __shfl_xor(sq, 32);
      float mean = sm * (1.f / 32.f);
      float inv  = rsqrtf(sq * (1.f / 32.f) - mean * mean + 1e-5f);
      f32x2 mean2 = {mean, mean}, inv2 = {inv, inv};
#pragma unroll
      for (int j = 0; j < 4; ++j) {
        f32x2 u = (vv2[j] - mean2) * inv2;
        u = pkfma(u, g1p[j], e1p[j]);
        u = __builtin_elementwise_max(u, z2);
        pkm[mt][j] = pack2(u[0], u[1]);
      }
    }
  }

  // ================= P2: QKV projection (B-frags gathered via ds_bpermute) =================
  {
#pragma unroll
    for (int mt = 0; mt < 5; ++mt) {
      int tokL = mt * 16 + li;
      FragU hb;
      {
        int p0 = __builtin_amdgcn_ds_bpermute(addrA, (int)pkm[mt][0]);
        int p2 = __builtin_amdgcn_ds_bpermute(addrA, (int)pkm[mt][2]);
        int p1 = __builtin_amdgcn_ds_bpermute(addrA, (int)pkm[mt][1]);
        int p3 = __builtin_amdgcn_ds_bpermute(addrA, (int)pkm[mt][3]);
        int q0 = __builtin_amdgcn_ds_bpermute(addrB, (int)pkm[mt][0]);
        int q2b = __builtin_amdgcn_ds_bpermute(addrB, (int)pkm[mt][2]);
        int q1 = __builtin_amdgcn_ds_bpermute(addrB, (int)pkm[mt][1]);
        int q3 = __builtin_amdgcn_ds_bpermute(addrB, (int)pkm[mt][3]);
        hb.u[0] = gl ? (uint32_t)p0 : (uint32_t)p2;
        hb.u[1] = gl ? (uint32_t)p1 : (uint32_t)p3;
        hb.u[2] = gl ? (uint32_t)q0 : (uint32_t)q2b;
        hb.u[3] = gl ? (uint32_t)q1 : (uint32_t)q3;
      }
#pragma unroll
      for (int ft = 0; ft < 6; ++ft) {
        f32x4 acc = __builtin_amdgcn_mfma_f32_16x16x32_bf16(wq[ft].v,  hb.v, bq[ft], 0, 0, 0);
        acc       = __builtin_amdgcn_mfma_f32_16x16x32_bf16(wql[ft].v, hb.v, acc,    0, 0, 0);
        int chq = (ft * 2 + (g >> 1)) ^ (tokL & 3);
        uint2 wr; wr.x = pack2(acc[0], acc[1]); wr.y = pack2(acc[2], acc[3]);
        *(uint2*)&qkv_lds[tokL * 48 + chq * 4 + (g & 1) * 2] = wr;
      }
    }
  }

  // ================= attention (packed f32 math) =================
  {
    int b_l = lane >> 2;
    int hh  = (lane >> 1) & 1;
    int cq  = hh * 2 + (lane & 1);

    f32x2 q2[5][4]; uint32_t kp[5][4], vp[5][4];
#pragma unroll
    for (int s = 0; s < 5; ++s) {
      int tok = b_l * 5 + s, key = tok & 3;
      uint4 qv = *(const uint4*)&qkv_lds[tok * 48 + (cq ^ key) * 4];
      q2[s][0] = up2v(qv.x); q2[s][1] = up2v(qv.y);
      q2[s][2] = up2v(qv.z); q2[s][3] = up2v(qv.w);
      uint4 kv = *(const uint4*)&qkv_lds[tok * 48 + ((4 + cq) ^ key) * 4];
      kp[s][0] = kv.x; kp[s][1] = kv.y; kp[s][2] = kv.z; kp[s][3] = kv.w;
      uint4 vv4 = *(const uint4*)&qkv_lds[tok * 48 + ((8 + cq) ^ key) * 4];
      vp[s][0] = vv4.x; vp[s][1] = vv4.y; vp[s][2] = vv4.z; vp[s][3] = vv4.w;
    }
    float sc[5][5];
#pragma unroll
    for (int s2 = 0; s2 < 5; ++s2) {
      f32x2 k0 = up2v(kp[s2][0]), k1 = up2v(kp[s2][1]);
      f32x2 k2 = up2v(kp[s2][2]), k3 = up2v(kp[s2][3]);
#pragma unroll
      for (int s1 = 0; s1 < 5; ++s1) {
        f32x2 acc = q2[s1][0] * k0;
        acc = pkfma(q2[s1][1], k1, acc);
        acc = pkfma(q2[s1][2], k2, acc);
        acc = pkfma(q2[s1][3], k3, acc);
        sc[s1][s2] = acc[0] + acc[1];
      }
    }
#pragma unroll
    for (int s1 = 0; s1 < 5; ++s1)
#pragma unroll
      for (int s2 = 0; s2 < 5; ++s2) {
        float p = sc[s1][s2];
        p += __shfl_xor(p, 1);
        sc[s1][s2] = p;
      }
    const float C = 0.36067376022224085f;     // 0.25 * log2(e)
#pragma unroll
    for (int s1 = 0; s1 < 5; ++s1) {
      float m = fmaxf(fmaxf(fmaxf(sc[s1][0], sc[s1][1]), fmaxf(sc[s1][2], sc[s1][3])), sc[s1][4]);
      float ssum = 0.f;
#pragma unroll
      for (int s2 = 0; s2 < 5; ++s2) {
        float e = __builtin_amdgcn_exp2f((sc[s1][s2] - m) * C);
        sc[s1][s2] = e; ssum += e;
      }
      float rs = __builtin_amdgcn_rcpf(ssum);
#pragma unroll
      for (int s2 = 0; s2 < 5; ++s2) sc[s1][s2] *= rs;
    }
    f32x2 o2[5][4];
#pragma unroll
    for (int s1 = 0; s1 < 5; ++s1)
#pragma unroll
      for (int j = 0; j < 4; ++j) o2[s1][j] = z2;
#pragma unroll
    for (int s2 = 0; s2 < 5; ++s2) {
      f32x2 v0 = up2v(vp[s2][0]), v1 = up2v(vp[s2][1]);
      f32x2 v2 = up2v(vp[s2][2]), v3 = up2v(vp[s2][3]);
#pragma unroll
      for (int s1 = 0; s1 < 5; ++s1) {
        f32x2 pp = {sc[s1][s2], sc[s1][s2]};
        o2[s1][0] = pkfma(pp, v0, o2[s1][0]);
        o2[s1][1] = pkfma(pp, v1, o2[s1][1]);
        o2[s1][2] = pkfma(pp, v2, o2[s1][2]);
        o2[s1][3] = pkfma(pp, v3, o2[s1][3]);
      }
    }
#pragma unroll
    for (int s1 = 0; s1 < 5; ++s1) {
      int tok = b_l * 5 + s1;
      uint4 wr;
      wr.x = pack2(o2[s1][0][0], o2[s1][0][1]); wr.y = pack2(o2[s1][1][0], o2[s1][1][1]);
      wr.z = pack2(o2[s1][2][0], o2[s1][2][1]); wr.w = pack2(o2[s1][3][0], o2[s1][3][1]);
      *(uint4*)&qkv_lds[tok * 48 + (cq ^ (tok & 3)) * 4] = wr;
    }
  }

  // ================= P3: out_proj + residual(regs) + LN2 -> h2 into k-chunks =================
  {
#pragma unroll
    for (int mt = 0; mt < 5; ++mt) {
      int tokL = mt * 16 + li;
      int ch = g ^ (tokL & 3);
      uint4 ov = *(const uint4*)&qkv_lds[tokL * 48 + ch * 4];
      FragU ob; ob.q = ov;
      f32x4 a0 = __builtin_amdgcn_mfma_f32_16x16x32_bf16(wof[0].v,  ob.v, boin[0], 0, 0, 0);
      a0       = __builtin_amdgcn_mfma_f32_16x16x32_bf16(wolf[0].v, ob.v, a0,      0, 0, 0);
      f32x4 a1 = __builtin_amdgcn_mfma_f32_16x16x32_bf16(wof[1].v,  ob.v, boin[1], 0, 0, 0);
      a1       = __builtin_amdgcn_mfma_f32_16x16x32_bf16(wolf[1].v, ob.v, a1,      0, 0, 0);
      f32x2 vv2[4];
      {
        f32x2 r0 = up2v(pkm[mt][0]), r1 = up2v(pkm[mt][1]);
        f32x2 r2 = up2v(pkm[mt][2]), r3 = up2v(pkm[mt][3]);
        f32x2 p0; p0[0] = a0[0]; p0[1] = a0[1];
        f32x2 p1; p1[0] = a0[2]; p1[1] = a0[3];
        f32x2 p2; p2[0] = a1[0]; p2[1] = a1[1];
        f32x2 p3; p3[0] = a1[2]; p3[1] = a1[3];
        vv2[0] = p0 + r0; vv2[1] = p1 + r1; vv2[2] = p2 + r2; vv2[3] = p3 + r3;
      }
      f32x2 s2 = (vv2[0] + vv2[1]) + (vv2[2] + vv2[3]);
      f32x2 q2 = vv2[0] * vv2[0];
      q2 = pkfma(vv2[1], vv2[1], q2); q2 = pkfma(vv2[2], vv2[2], q2); q2 = pkfma(vv2[3], vv2[3], q2);
      float sm = s2[0] + s2[1], sq = q2[0] + q2[1];
      sm += __shfl_xor(sm, 16); sm += __shfl_xor(sm, 32);
      sq += __shfl_xor(sq, 16); sq += __shfl_xor(sq, 32);
      float mean = sm * (1.f / 32.f);
      float inv  = rsqrtf(sq * (1.f / 32.f) - mean * mean + 1e-5f);
      f32x2 mean2 = {mean, mean}, inv2 = {inv, inv};
      uint32_t pk[4];
#pragma unroll
      for (int j = 0; j < 4; ++j) {
        f32x2 u = (vv2[j] - mean2) * inv2;
        u = pkfma(u, g2p[j], e2p[j]);
        pk[j] = pack2(u[0], u[1]);
      }
      // h2 -> chunks 4..7 (old k region, dead after attention)
#pragma unroll
      for (int t = 0; t < 2; ++t) {
        int chh = (4 + t * 2 + (g >> 1)) ^ (tokL & 3);
        uint2 wr; wr.x = pk[t*2]; wr.y = pk[t*2+1];
        *(uint2*)&qkv_lds[tokL * 48 + chh * 4 + (g & 1) * 2] = wr;
      }
    }
  }

  // ================= P4: output_proj (160 -> 64) + LN3 =================
  {
    int batL = li;
    f32x4 acc[4];
#pragma unroll
    for (int ot = 0; ot < 4; ++ot) acc[ot] = *(const f32x4*)&b3[ot * 16 + g * 4];
#pragma unroll
    for (int kt = 0; kt < 5; ++kt) {
      int tokL = batL * 5 + kt;
      int ch = (4 + g) ^ (tokL & 3);
      uint4 hv = *(const uint4*)&qkv_lds[tokL * 48 + ch * 4];
      FragU hb; hb.q = hv;
#pragma unroll
      for (int ot = 0; ot < 4; ++ot) {
        FragU fh, fl;
        fh.q = *(const uint4*)&ws[WS_W3H + (ot * 16 + li) * 80 + kt * 16 + g * 4];
        fl.q = *(const uint4*)&ws[WS_W3L + (ot * 16 + li) * 80 + kt * 16 + g * 4];
        acc[ot] = __builtin_amdgcn_mfma_f32_16x16x32_bf16(fh.v, hb.v, acc[ot], 0, 0, 0);
        acc[ot] = __builtin_amdgcn_mfma_f32_16x16x32_bf16(fl.v, hb.v, acc[ot], 0, 0, 0);
      }
    }
    f32x2 a2[8];
#pragma unroll
    for (int ot = 0; ot < 4; ++ot) {
      a2[ot*2][0] = acc[ot][0]; a2[ot*2][1] = acc[ot][1];
      a2[ot*2+1][0] = acc[ot][2]; a2[ot*2+1][1] = acc[ot][3];
    }
    f32x2 s2v = ((a2[0] + a2[1]) + (a2[2] + a2[3])) + ((a2[4] + a2[5]) + (a2[6] + a2[7]));
    f32x2 q2v = a2[0] * a2[0];
#pragma unroll
    for (int j = 1; j < 8; ++j) q2v = pkfma(a2[j], a2[j], q2v);
    float sm = s2v[0] + s2v[1], sq = q2v[0] + q2v[1];
    sm += __shfl_xor(sm, 16); sm += __shfl_xor(sm, 32);
    sq += __shfl_xor(sq, 16); sq += __shfl_xor(sq, 32);
    float mean = sm * (1.f / 64.f);
    float inv  = rsqrtf(sq * (1.f / 64.f) - mean * mean + 1e-5f);
    f32x2 mean2 = {mean, mean}, inv2 = {inv, inv};
    float* op = out + (size_t)(b0 + batL) * OUTD;
#pragma unroll
    for (int ot = 0; ot < 4; ++ot) {
      f32x2 u0 = (a2[ot*2]   - mean2) * inv2;
      f32x2 u1 = (a2[ot*2+1] - mean2) * inv2;
      u0 = pkfma(u0, *(const f32x2*)&g3[ot * 16 + g * 4],     *(const f32x2*)&be3[ot * 16 + g * 4]);
      u1 = pkfma(u1, *(const f32x2*)&g3[ot * 16 + g * 4 + 2], *(const f32x2*)&be3[ot * 16 + g * 4 + 2]);
      float4 st; st.x = u0[0]; st.y = u0[1]; st.z = u1[0]; st.w = u1[1];
      *(float4*)&op[ot * 16 + g * 4] = st;
    }
  }
}

extern "C" void kernel_launch(void* const* d_in, const int* in_sizes, int n_in,
                              void* d_out, int out_size, void* d_ws, size_t ws_size,
                              hipStream_t stream) {
  const float* x    = (const float*)d_in[0];
  const float* W1   = (const float*)d_in[1];
  const float* b1   = (const float*)d_in[2];
  const float* g1   = (const float*)d_in[3];
  const float* be1  = (const float*)d_in[4];
  const float* Wqkv = (const float*)d_in[5];
  const float* bqkv = (const float*)d_in[6];
  const float* Wo   = (const float*)d_in[7];
  const float* bo   = (const float*)d_in[8];
  const float* g2   = (const float*)d_in[9];
  const float* be2  = (const float*)d_in[10];
  const float* W3   = (const float*)d_in[11];
  const float* b3   = (const float*)d_in[12];
  const float* g3   = (const float*)d_in[13];
  const float* be3  = (const float*)d_in[14];
  float* out = (float*)d_out;
  uint32_t* ws = (uint32_t*)d_ws;

  prep_weights<<<dim3((WS_TOTAL + 255) / 256), dim3(256), 0, stream>>>(W1, Wqkv, Wo, W3, ws);

  const int nbatch  = in_sizes[0] / SF;   // 262144
  const int nblocks = nbatch / TB;        // 16384

  fused_exec_encoder<<<dim3(nblocks), dim3(NTHR), 0, stream>>>(
      x, b1, g1, be1, bqkv, bo, g2, be2, b3, g3, be3, ws, out);
}